// Round 1
// baseline (422.365 us; speedup 1.0000x reference)
//
#include <hip/hip_runtime.h>

#define B_ 8
#define N_ 1024
#define D_ 768
#define H_ 12
#define HD 64
#define M_ (B_*N_)
#define N3 (3*D_)

typedef short short8 __attribute__((ext_vector_type(8)));
typedef float f32x4 __attribute__((ext_vector_type(4)));

__device__ __forceinline__ unsigned short f2bf(float f) {
    union { float f; unsigned int u; } c; c.f = f;
    unsigned int u = c.u;
    unsigned int r = (u + 0x7fffu + ((u >> 16) & 1u)) >> 16;
    return (unsigned short)r;
}

// ---------------- cast / transpose kernels ----------------

__global__ void cast_x_kernel(const float* __restrict__ in,
                              unsigned short* __restrict__ out, int n4) {
    int i = blockIdx.x * blockDim.x + threadIdx.x;
    if (i >= n4) return;
    float4 v = reinterpret_cast<const float4*>(in)[i];
    ushort4 o;
    o.x = f2bf(v.x); o.y = f2bf(v.y); o.z = f2bf(v.z); o.w = f2bf(v.w);
    reinterpret_cast<ushort4*>(out)[i] = o;
}

__global__ void transpose_cast_kernel(const float* __restrict__ w,
                                      unsigned short* __restrict__ wT,
                                      int R, int C) {
    int i = blockIdx.x * blockDim.x + threadIdx.x;
    if (i >= R * C) return;
    int r = i / C, c = i - r * C;
    wT[c * R + r] = f2bf(w[i]);
}

// ---------------- GEMM: C[M,N] = A[M,K] @ Bt[N,K]^T + bias ----------------
// MODE 0: scatter to q/k/v [B,H,N,hd] bf16 (scale folded into q)
// MODE 1: write fp32 to outf [M,N]

template<int MODE>
__global__ __launch_bounds__(256) void gemm_kernel(
    const unsigned short* __restrict__ A,
    const unsigned short* __restrict__ Bt,
    const float* __restrict__ bias,
    float* __restrict__ outf,
    unsigned short* __restrict__ qo,
    unsigned short* __restrict__ ko,
    unsigned short* __restrict__ vo,
    int Ndim, int K)
{
    int lane = threadIdx.x & 63;
    int w = threadIdx.x >> 6;
    int wr = w >> 1, wc = w & 1;
    int baseRow = blockIdx.y * 64 + wr * 32;
    int baseCol = blockIdx.x * 64 + wc * 32;
    int lr = lane & 15;
    int lk = (lane >> 4) * 8;

    f32x4 acc[2][2] = {};
    const unsigned short* a0p = A + (size_t)(baseRow + lr) * K + lk;
    const unsigned short* a1p = A + (size_t)(baseRow + 16 + lr) * K + lk;
    const unsigned short* b0p = Bt + (size_t)(baseCol + lr) * K + lk;
    const unsigned short* b1p = Bt + (size_t)(baseCol + 16 + lr) * K + lk;

    for (int k0 = 0; k0 < K; k0 += 32) {
        short8 a0 = *reinterpret_cast<const short8*>(a0p + k0);
        short8 a1 = *reinterpret_cast<const short8*>(a1p + k0);
        short8 b0 = *reinterpret_cast<const short8*>(b0p + k0);
        short8 b1 = *reinterpret_cast<const short8*>(b1p + k0);
        acc[0][0] = __builtin_amdgcn_mfma_f32_16x16x32_bf16(a0, b0, acc[0][0], 0, 0, 0);
        acc[0][1] = __builtin_amdgcn_mfma_f32_16x16x32_bf16(a0, b1, acc[0][1], 0, 0, 0);
        acc[1][0] = __builtin_amdgcn_mfma_f32_16x16x32_bf16(a1, b0, acc[1][0], 0, 0, 0);
        acc[1][1] = __builtin_amdgcn_mfma_f32_16x16x32_bf16(a1, b1, acc[1][1], 0, 0, 0);
    }

    int orow = (lane >> 4) * 4;
    int ocol = lane & 15;
    #pragma unroll
    for (int mi = 0; mi < 2; mi++) {
        #pragma unroll
        for (int ni = 0; ni < 2; ni++) {
            int col = baseCol + ni * 16 + ocol;
            float bv = bias[col];
            #pragma unroll
            for (int r = 0; r < 4; r++) {
                int row = baseRow + mi * 16 + orow + r;
                float val = acc[mi][ni][r] + bv;
                if (MODE == 1) {
                    outf[(size_t)row * Ndim + col] = val;
                } else {
                    int which = col / 768;
                    int rem = col - which * 768;
                    int h = rem >> 6, dd = rem & 63;
                    int b = row >> 10, nn = row & 1023;
                    unsigned short* dst = (which == 0) ? qo : (which == 1) ? ko : vo;
                    float o = val;
                    if (which == 0) o *= 0.125f;  // 1/sqrt(64)
                    dst[(((size_t)(b * H_ + h) * N_ + nn) * HD) + dd] = f2bf(o);
                }
            }
        }
    }
}

// ---------------- Flash attention ----------------
// grid: (N/64, B*H), block 256. Wave w handles q rows [qt*64+w*16, +16)

__global__ __launch_bounds__(256) void attn_kernel(
    const unsigned short* __restrict__ qg,
    const unsigned short* __restrict__ kg,
    const unsigned short* __restrict__ vg,
    unsigned short* __restrict__ aout)
{
    __shared__ unsigned short Kt[64][72];
    __shared__ unsigned short Vt[64][72];
    __shared__ unsigned short Pt[4][16][72];

    int tid = threadIdx.x;
    int lane = tid & 63, w = tid >> 6;
    int bh = blockIdx.y;
    int b = bh / H_, h = bh - b * H_;
    int q0 = blockIdx.x * 64 + w * 16;
    int lr = lane & 15, lk = (lane >> 4) * 8;

    const unsigned short* qbase = qg + (((size_t)(b * H_ + h) * N_) + q0) * HD;
    short8 qf0 = *reinterpret_cast<const short8*>(qbase + lr * HD + lk);
    short8 qf1 = *reinterpret_cast<const short8*>(qbase + lr * HD + lk + 32);

    const unsigned short* kbase = kg + ((size_t)(b * H_ + h) * N_) * HD;
    const unsigned short* vbase = vg + ((size_t)(b * H_ + h) * N_) * HD;

    float m_run[4], l_run[4];
    f32x4 o_acc[4] = {};
    #pragma unroll
    for (int r = 0; r < 4; r++) { m_run[r] = -INFINITY; l_run[r] = 0.f; }

    int ldrow = tid >> 2;
    int ldc = (tid & 3) * 16;

    for (int kv0 = 0; kv0 < N_; kv0 += 64) {
        __syncthreads();
        {
            const uint4* gk = reinterpret_cast<const uint4*>(kbase + (size_t)(kv0 + ldrow) * HD + ldc);
            uint4* sk = reinterpret_cast<uint4*>(&Kt[ldrow][ldc]);
            sk[0] = gk[0]; sk[1] = gk[1];
            const uint4* gv = reinterpret_cast<const uint4*>(vbase + (size_t)(kv0 + ldrow) * HD + ldc);
            uint4* sv = reinterpret_cast<uint4*>(&Vt[ldrow][ldc]);
            sv[0] = gv[0]; sv[1] = gv[1];
        }
        __syncthreads();

        // S = Q K^T  (16 q-rows x 64 keys per wave)
        f32x4 s[4] = {};
        #pragma unroll
        for (int ct = 0; ct < 4; ct++) {
            short8 kf0 = *reinterpret_cast<const short8*>(&Kt[ct * 16 + lr][lk]);
            short8 kf1 = *reinterpret_cast<const short8*>(&Kt[ct * 16 + lr][lk + 32]);
            s[ct] = __builtin_amdgcn_mfma_f32_16x16x32_bf16(qf0, kf0, s[ct], 0, 0, 0);
            s[ct] = __builtin_amdgcn_mfma_f32_16x16x32_bf16(qf1, kf1, s[ct], 0, 0, 0);
        }

        // online softmax: rows r live in lanes with same (lane>>4), cols = lane&15 + 16*ct
        float mx[4], alpha[4], sm[4];
        #pragma unroll
        for (int r = 0; r < 4; r++) {
            float m = fmaxf(fmaxf(s[0][r], s[1][r]), fmaxf(s[2][r], s[3][r]));
            #pragma unroll
            for (int off = 1; off < 16; off <<= 1) m = fmaxf(m, __shfl_xor(m, off, 64));
            float mn = fmaxf(m_run[r], m);
            alpha[r] = expf(m_run[r] - mn);
            mx[r] = mn;
            sm[r] = 0.f;
        }
        int prow = (lane >> 4) * 4;
        #pragma unroll
        for (int ct = 0; ct < 4; ct++) {
            #pragma unroll
            for (int r = 0; r < 4; r++) {
                float p = expf(s[ct][r] - mx[r]);
                sm[r] += p;
                Pt[w][prow + r][ct * 16 + lr] = f2bf(p);
            }
        }
        #pragma unroll
        for (int r = 0; r < 4; r++) {
            float t = sm[r];
            #pragma unroll
            for (int off = 1; off < 16; off <<= 1) t += __shfl_xor(t, off, 64);
            l_run[r] = l_run[r] * alpha[r] + t;
            m_run[r] = mx[r];
        }
        #pragma unroll
        for (int ct = 0; ct < 4; ct++)
            #pragma unroll
            for (int r = 0; r < 4; r++) o_acc[ct][r] *= alpha[r];

        __syncthreads();  // ensure P visible (and keeps waves in step)

        // O += P @ V
        #pragma unroll
        for (int ks = 0; ks < 2; ks++) {
            short8 pa = *reinterpret_cast<const short8*>(&Pt[w][lr][ks * 32 + lk]);
            #pragma unroll
            for (int ct = 0; ct < 4; ct++) {
                short8 vb;
                #pragma unroll
                for (int j = 0; j < 8; j++)
                    vb[j] = (short)Vt[ks * 32 + lk + j][ct * 16 + lr];
                o_acc[ct] = __builtin_amdgcn_mfma_f32_16x16x32_bf16(pa, vb, o_acc[ct], 0, 0, 0);
            }
        }
    }

    int orow = (lane >> 4) * 4;
    #pragma unroll
    for (int ct = 0; ct < 4; ct++) {
        #pragma unroll
        for (int r = 0; r < 4; r++) {
            float val = o_acc[ct][r] / l_run[r];
            int n = q0 + orow + r;
            aout[((size_t)(b * N_ + n)) * D_ + h * HD + ct * 16 + lr] = f2bf(val);
        }
    }
}

// ---------------- launch ----------------

extern "C" void kernel_launch(void* const* d_in, const int* in_sizes, int n_in,
                              void* d_out, int out_size, void* d_ws, size_t ws_size,
                              hipStream_t stream) {
    const float* x      = (const float*)d_in[0];
    const float* w_qkv  = (const float*)d_in[1];
    const float* b_qkv  = (const float*)d_in[2];
    const float* w_proj = (const float*)d_in[3];
    const float* b_proj = (const float*)d_in[4];
    float* out = (float*)d_out;

    char* ws = (char*)d_ws;
    unsigned short* xb     = (unsigned short*)(ws + 0);          // 12582912 B
    unsigned short* wqkvT  = (unsigned short*)(ws + 12582912);   // 3538944 B
    unsigned short* wprojT = (unsigned short*)(ws + 16121856);   // 1179648 B
    unsigned short* qb     = (unsigned short*)(ws + 17301504);   // 12582912 B
    unsigned short* kb     = (unsigned short*)(ws + 29884416);   // 12582912 B
    unsigned short* vb     = (unsigned short*)(ws + 42467328);   // 12582912 B  (end ~55 MB)
    unsigned short* aout   = xb;  // alias: x no longer needed after GEMM1

    cast_x_kernel<<<6144, 256, 0, stream>>>(x, xb, 1572864);
    transpose_cast_kernel<<<6912, 256, 0, stream>>>(w_qkv, wqkvT, 768, 2304);
    transpose_cast_kernel<<<2304, 256, 0, stream>>>(w_proj, wprojT, 768, 768);

    gemm_kernel<0><<<dim3(36, 128), 256, 0, stream>>>(
        xb, wqkvT, b_qkv, nullptr, qb, kb, vb, N3, D_);

    attn_kernel<<<dim3(16, 96), 256, 0, stream>>>(qb, kb, vb, aout);

    gemm_kernel<1><<<dim3(12, 128), 256, 0, stream>>>(
        aout, wprojT, b_proj, out, nullptr, nullptr, nullptr, D_, D_);
}

// Round 2
// 306.563 us; speedup vs baseline: 1.3777x; 1.3777x over previous
//
#include <hip/hip_runtime.h>

#define B_ 8
#define N_ 1024
#define D_ 768
#define H_ 12
#define HD 64
#define M_ (B_*N_)

typedef short short8 __attribute__((ext_vector_type(8)));
typedef float f32x4 __attribute__((ext_vector_type(4)));

__device__ __forceinline__ unsigned short f2bf(float f) {
    union { float f; unsigned int u; } c; c.f = f;
    unsigned int u = c.u;
    unsigned int r = (u + 0x7fffu + ((u >> 16) & 1u)) >> 16;
    return (unsigned short)r;
}

__device__ __forceinline__ void gload16(const void* g, void* l) {
    __builtin_amdgcn_global_load_lds(
        (const __attribute__((address_space(1))) unsigned int*)g,
        (__attribute__((address_space(3))) unsigned int*)l, 16, 0, 0);
}

// ---------------- cast / transpose kernels ----------------

__global__ void cast_x_kernel(const float* __restrict__ in,
                              unsigned short* __restrict__ out, int n4) {
    int i = blockIdx.x * blockDim.x + threadIdx.x;
    if (i >= n4) return;
    float4 v = reinterpret_cast<const float4*>(in)[i];
    ushort4 o;
    o.x = f2bf(v.x); o.y = f2bf(v.y); o.z = f2bf(v.z); o.w = f2bf(v.w);
    reinterpret_cast<ushort4*>(out)[i] = o;
}

__global__ void transpose_cast_kernel(const float* __restrict__ w,
                                      unsigned short* __restrict__ wT,
                                      int R, int C) {
    int i = blockIdx.x * blockDim.x + threadIdx.x;
    if (i >= R * C) return;
    int r = i / C, c = i - r * C;
    wT[c * R + r] = f2bf(w[i]);
}

// V [B*H][N][64] -> V^T [B*H][64][N], LDS-tiled
__global__ __launch_bounds__(256) void transpose_v_kernel(
    const unsigned short* __restrict__ vin,
    unsigned short* __restrict__ vout)
{
    __shared__ unsigned short T[64][72];
    int bh = blockIdx.y;
    int n0 = blockIdx.x * 64;
    int t = threadIdx.x;
    int r = t >> 2;
    int c = (t & 3) * 16;
    const uint4* g = reinterpret_cast<const uint4*>(vin + ((size_t)bh * N_ + n0 + r) * HD + c);
    uint4 a = g[0], b2 = g[1];
    *reinterpret_cast<uint4*>(&T[r][c]) = a;
    *reinterpret_cast<uint4*>(&T[r][c + 8]) = b2;
    __syncthreads();
    int d = t >> 2;
    int nc = (t & 3) * 16;
    unsigned short tmp[16];
    #pragma unroll
    for (int j = 0; j < 16; j++) tmp[j] = T[nc + j][d];
    uint4* o = reinterpret_cast<uint4*>(vout + ((size_t)bh * HD + d) * N_ + n0 + nc);
    o[0] = *reinterpret_cast<const uint4*>(&tmp[0]);
    o[1] = *reinterpret_cast<const uint4*>(&tmp[8]);
}

// ---------------- GEMM (m97 structure): C[M,N] = A[M,K] @ Bt[N,K]^T + bias ----
// 128x128 tile, BK=32, 4 waves (2x2), each wave 4x4 16x16 frags.
// MODE 0: scatter to q/k/v [B,H,N,hd] bf16 (scale folded into q)
// MODE 1: write fp32 to outf [M,N]

template<int MODE>
__global__ __launch_bounds__(256) void gemm_kernel(
    const unsigned short* __restrict__ A,
    const unsigned short* __restrict__ Bt,
    const float* __restrict__ bias,
    float* __restrict__ outf,
    unsigned short* __restrict__ qo,
    unsigned short* __restrict__ ko,
    unsigned short* __restrict__ vo,
    int Ndim, int K)
{
    __shared__ unsigned short As[128 * 32];
    __shared__ unsigned short Bs[128 * 32];

    int tid = threadIdx.x;
    int lane = tid & 63, w = tid >> 6;
    int wr = w >> 1, wc = w & 1;
    int m0 = blockIdx.y * 128, n0 = blockIdx.x * 128;
    int lr = lane & 15, lk8 = (lane >> 4) * 8;

    // staging: thread t covers LDS bytes [t*16, t*16+16) => row t/4, k-elems (t%4)*8
    int srow = tid >> 2;
    int selem = (tid & 3) * 8;
    const unsigned short* gA = A + (size_t)(m0 + srow) * K + selem;
    const unsigned short* gB = Bt + (size_t)(n0 + srow) * K + selem;
    unsigned short* lA = As + w * 512;   // wave-uniform LDS base (1024 B per wave)
    unsigned short* lB = Bs + w * 512;

    f32x4 acc[4][4] = {};

    for (int k0 = 0; k0 < K; k0 += 32) {
        __syncthreads();
        gload16(gA + k0, lA);
        gload16(gA + (size_t)64 * K + k0, lA + 2048);
        gload16(gB + k0, lB);
        gload16(gB + (size_t)64 * K + k0, lB + 2048);
        __syncthreads();

        short8 af[4], bf[4];
        #pragma unroll
        for (int mi = 0; mi < 4; mi++)
            af[mi] = *reinterpret_cast<const short8*>(&As[(wr * 64 + mi * 16 + lr) * 32 + lk8]);
        #pragma unroll
        for (int ni = 0; ni < 4; ni++)
            bf[ni] = *reinterpret_cast<const short8*>(&Bs[(wc * 64 + ni * 16 + lr) * 32 + lk8]);
        #pragma unroll
        for (int mi = 0; mi < 4; mi++)
            #pragma unroll
            for (int ni = 0; ni < 4; ni++)
                acc[mi][ni] = __builtin_amdgcn_mfma_f32_16x16x32_bf16(af[mi], bf[ni], acc[mi][ni], 0, 0, 0);
    }

    int org = (lane >> 4) * 4;   // output row group
    if (MODE == 1) {
        #pragma unroll
        for (int mi = 0; mi < 4; mi++) {
            #pragma unroll
            for (int ni = 0; ni < 4; ni++) {
                int col = n0 + wc * 64 + ni * 16 + lr;
                float bv = bias[col];
                #pragma unroll
                for (int r = 0; r < 4; r++) {
                    int row = m0 + wr * 64 + mi * 16 + org + r;
                    outf[(size_t)row * Ndim + col] = acc[mi][ni][r] + bv;
                }
            }
        }
    } else {
        int which = n0 / 768;                 // uniform per block (128 | 768)
        unsigned short* dst = (which == 0) ? qo : (which == 1) ? ko : vo;
        float fold = (which == 0) ? 0.125f : 1.0f;   // 1/sqrt(hd) folded into q
        #pragma unroll
        for (int mi = 0; mi < 4; mi++) {
            #pragma unroll
            for (int ni = 0; ni < 4; ni++) {
                int col = n0 + wc * 64 + ni * 16 + lr;
                int rem = col - which * 768;
                int h = rem >> 6, dd = rem & 63;
                float bv = bias[col];
                #pragma unroll
                for (int r = 0; r < 4; r++) {
                    int row = m0 + wr * 64 + mi * 16 + org + r;
                    int b = row >> 10, nn = row & 1023;
                    float o = (acc[mi][ni][r] + bv) * fold;
                    dst[(((size_t)(b * H_ + h) * N_ + nn) * HD) + dd] = f2bf(o);
                }
            }
        }
    }
}

// ---------------- Flash attention (no K/V staging; V^T direct-global) -------
// grid: (N/64, B*H), block 256. Wave w owns q rows [qt*64+w*16, +16); no barriers.

__global__ __launch_bounds__(256) void attn_kernel(
    const unsigned short* __restrict__ qg,
    const unsigned short* __restrict__ kg,
    const unsigned short* __restrict__ vtg,
    unsigned short* __restrict__ aout)
{
    __shared__ alignas(16) unsigned short Pt[4][16][80];

    int tid = threadIdx.x;
    int lane = tid & 63, w = tid >> 6;
    int bh = blockIdx.y;
    int b = bh / H_, h = bh - b * H_;
    int q0 = blockIdx.x * 64 + w * 16;
    int lr = lane & 15, lk = (lane >> 4) * 8;

    const unsigned short* qbase = qg + (((size_t)bh * N_) + q0) * HD;
    short8 qf0 = *reinterpret_cast<const short8*>(qbase + lr * HD + lk);
    short8 qf1 = *reinterpret_cast<const short8*>(qbase + lr * HD + lk + 32);

    const unsigned short* kbase = kg + ((size_t)bh * N_) * HD + lr * HD + lk;
    const unsigned short* vtbase = vtg + ((size_t)bh * HD) * N_ + lr * N_ + lk;

    float m_run[4], l_run[4];
    f32x4 o_acc[4] = {};
    #pragma unroll
    for (int r = 0; r < 4; r++) { m_run[r] = -INFINITY; l_run[r] = 0.f; }

    for (int kv0 = 0; kv0 < N_; kv0 += 64) {
        // S = Q K^T : B-frags straight from global (L1/L2-resident)
        f32x4 s[4] = {};
        #pragma unroll
        for (int ct = 0; ct < 4; ct++) {
            const unsigned short* kp = kbase + (size_t)(kv0 + ct * 16) * HD;
            short8 kf0 = *reinterpret_cast<const short8*>(kp);
            short8 kf1 = *reinterpret_cast<const short8*>(kp + 32);
            s[ct] = __builtin_amdgcn_mfma_f32_16x16x32_bf16(qf0, kf0, s[ct], 0, 0, 0);
            s[ct] = __builtin_amdgcn_mfma_f32_16x16x32_bf16(qf1, kf1, s[ct], 0, 0, 0);
        }

        // online softmax (rows r: col = lane&15 within 16-lane group)
        float mx[4], alpha[4], sm[4];
        #pragma unroll
        for (int r = 0; r < 4; r++) {
            float m = fmaxf(fmaxf(s[0][r], s[1][r]), fmaxf(s[2][r], s[3][r]));
            #pragma unroll
            for (int off = 1; off < 16; off <<= 1) m = fmaxf(m, __shfl_xor(m, off, 64));
            float mn = fmaxf(m_run[r], m);
            alpha[r] = __expf(m_run[r] - mn);
            mx[r] = mn;
            sm[r] = 0.f;
        }
        int prow = (lane >> 4) * 4;
        #pragma unroll
        for (int ct = 0; ct < 4; ct++) {
            #pragma unroll
            for (int r = 0; r < 4; r++) {
                float p = __expf(s[ct][r] - mx[r]);
                sm[r] += p;
                Pt[w][prow + r][ct * 16 + lr] = f2bf(p);
            }
        }
        #pragma unroll
        for (int r = 0; r < 4; r++) {
            float t = sm[r];
            #pragma unroll
            for (int off = 1; off < 16; off <<= 1) t += __shfl_xor(t, off, 64);
            l_run[r] = l_run[r] * alpha[r] + t;
            m_run[r] = mx[r];
        }
        #pragma unroll
        for (int ct = 0; ct < 4; ct++)
            #pragma unroll
            for (int r = 0; r < 4; r++) o_acc[ct][r] *= alpha[r];

        // O += P @ V : A-frag via per-wave LDS bounce, B-frag from V^T global
        #pragma unroll
        for (int ks = 0; ks < 2; ks++) {
            short8 pa = *reinterpret_cast<const short8*>(&Pt[w][lr][ks * 32 + lk]);
            #pragma unroll
            for (int ct = 0; ct < 4; ct++) {
                short8 vf = *reinterpret_cast<const short8*>(
                    vtbase + (size_t)(ct * 16) * N_ + kv0 + ks * 32);
                o_acc[ct] = __builtin_amdgcn_mfma_f32_16x16x32_bf16(pa, vf, o_acc[ct], 0, 0, 0);
            }
        }
    }

    int orow = (lane >> 4) * 4;
    #pragma unroll
    for (int ct = 0; ct < 4; ct++) {
        #pragma unroll
        for (int r = 0; r < 4; r++) {
            float val = o_acc[ct][r] / l_run[r];
            int n = q0 + orow + r;
            aout[((size_t)(b * N_ + n)) * D_ + h * HD + ct * 16 + lr] = f2bf(val);
        }
    }
}

// ---------------- launch ----------------

extern "C" void kernel_launch(void* const* d_in, const int* in_sizes, int n_in,
                              void* d_out, int out_size, void* d_ws, size_t ws_size,
                              hipStream_t stream) {
    const float* x      = (const float*)d_in[0];
    const float* w_qkv  = (const float*)d_in[1];
    const float* b_qkv  = (const float*)d_in[2];
    const float* w_proj = (const float*)d_in[3];
    const float* b_proj = (const float*)d_in[4];
    float* out = (float*)d_out;

    char* ws = (char*)d_ws;
    unsigned short* xb     = (unsigned short*)(ws + 0);          // 12.6 MB (aliased as attn out)
    unsigned short* wqkvT  = (unsigned short*)(ws + 12582912);   // 3.5 MB
    unsigned short* wprojT = (unsigned short*)(ws + 16121856);   // 1.2 MB
    unsigned short* qb     = (unsigned short*)(ws + 17301504);   // 12.6 MB
    unsigned short* kb     = (unsigned short*)(ws + 29884416);   // 12.6 MB
    unsigned short* vb     = (unsigned short*)(ws + 42467328);   // 12.6 MB
    unsigned short* vtb    = (unsigned short*)(ws + 55050240);   // 12.6 MB (end ~67.6 MB)
    unsigned short* aout   = xb;  // x dead after gemm<0>

    cast_x_kernel<<<6144, 256, 0, stream>>>(x, xb, 1572864);
    transpose_cast_kernel<<<6912, 256, 0, stream>>>(w_qkv, wqkvT, 768, 2304);
    transpose_cast_kernel<<<2304, 256, 0, stream>>>(w_proj, wprojT, 768, 768);

    gemm_kernel<0><<<dim3(18, 64), 256, 0, stream>>>(
        xb, wqkvT, b_qkv, nullptr, qb, kb, vb, 3 * D_, D_);

    transpose_v_kernel<<<dim3(16, 96), 256, 0, stream>>>(vb, vtb);

    attn_kernel<<<dim3(16, 96), 256, 0, stream>>>(qb, kb, vtb, aout);

    gemm_kernel<1><<<dim3(6, 64), 256, 0, stream>>>(
        aout, wprojT, b_proj, out, nullptr, nullptr, nullptr, D_, D_);
}

// Round 3
// 192.547 us; speedup vs baseline: 2.1936x; 1.5921x over previous
//
#include <hip/hip_runtime.h>

#define B_ 8
#define N_ 1024
#define D_ 768
#define H_ 12
#define HD 64
#define M_ (B_*N_)

typedef short short8 __attribute__((ext_vector_type(8)));
typedef float f32x4 __attribute__((ext_vector_type(4)));

__device__ __forceinline__ unsigned short f2bf(float f) {
    union { float f; unsigned int u; } c; c.f = f;
    unsigned int u = c.u;
    unsigned int r = (u + 0x7fffu + ((u >> 16) & 1u)) >> 16;
    return (unsigned short)r;
}

__device__ __forceinline__ void gload16(const void* g, void* l) {
    __builtin_amdgcn_global_load_lds(
        (const __attribute__((address_space(1))) unsigned int*)g,
        (__attribute__((address_space(3))) unsigned int*)l, 16, 0, 0);
}

// ---------------- cast / transpose kernels ----------------

__global__ void cast_x_kernel(const float* __restrict__ in,
                              unsigned short* __restrict__ out, int n4) {
    int i = blockIdx.x * blockDim.x + threadIdx.x;
    if (i >= n4) return;
    float4 v = reinterpret_cast<const float4*>(in)[i];
    ushort4 o;
    o.x = f2bf(v.x); o.y = f2bf(v.y); o.z = f2bf(v.z); o.w = f2bf(v.w);
    reinterpret_cast<ushort4*>(out)[i] = o;
}

__global__ void transpose_cast_kernel(const float* __restrict__ w,
                                      unsigned short* __restrict__ wT,
                                      int R, int C) {
    int i = blockIdx.x * blockDim.x + threadIdx.x;
    if (i >= R * C) return;
    int r = i / C, c = i - r * C;
    wT[c * R + r] = f2bf(w[i]);
}

// V [B*H][N][64] -> V^T [B*H][64][N], LDS-tiled
__global__ __launch_bounds__(256) void transpose_v_kernel(
    const unsigned short* __restrict__ vin,
    unsigned short* __restrict__ vout)
{
    __shared__ unsigned short T[64][72];
    int bh = blockIdx.y;
    int n0 = blockIdx.x * 64;
    int t = threadIdx.x;
    int r = t >> 2;
    int c = (t & 3) * 16;
    const uint4* g = reinterpret_cast<const uint4*>(vin + ((size_t)bh * N_ + n0 + r) * HD + c);
    uint4 a = g[0], b2 = g[1];
    *reinterpret_cast<uint4*>(&T[r][c]) = a;
    *reinterpret_cast<uint4*>(&T[r][c + 8]) = b2;
    __syncthreads();
    int d = t >> 2;
    int nc = (t & 3) * 16;
    unsigned short tmp[16];
    #pragma unroll
    for (int j = 0; j < 16; j++) tmp[j] = T[nc + j][d];
    uint4* o = reinterpret_cast<uint4*>(vout + ((size_t)bh * HD + d) * N_ + n0 + nc);
    o[0] = *reinterpret_cast<const uint4*>(&tmp[0]);
    o[1] = *reinterpret_cast<const uint4*>(&tmp[8]);
}

// ---------------- GEMM (m97 structure): C[M,N] = A[M,K] @ Bt[N,K]^T + bias ----

template<int MODE>
__global__ __launch_bounds__(256) void gemm_kernel(
    const unsigned short* __restrict__ A,
    const unsigned short* __restrict__ Bt,
    const float* __restrict__ bias,
    float* __restrict__ outf,
    unsigned short* __restrict__ qo,
    unsigned short* __restrict__ ko,
    unsigned short* __restrict__ vo,
    int Ndim, int K)
{
    __shared__ unsigned short As[128 * 32];
    __shared__ unsigned short Bs[128 * 32];

    int tid = threadIdx.x;
    int lane = tid & 63, w = tid >> 6;
    int wr = w >> 1, wc = w & 1;
    int m0 = blockIdx.y * 128, n0 = blockIdx.x * 128;
    int lr = lane & 15, lk8 = (lane >> 4) * 8;

    int srow = tid >> 2;
    int selem = (tid & 3) * 8;
    const unsigned short* gA = A + (size_t)(m0 + srow) * K + selem;
    const unsigned short* gB = Bt + (size_t)(n0 + srow) * K + selem;
    unsigned short* lA = As + w * 512;
    unsigned short* lB = Bs + w * 512;

    f32x4 acc[4][4] = {};

    for (int k0 = 0; k0 < K; k0 += 32) {
        __syncthreads();
        gload16(gA + k0, lA);
        gload16(gA + (size_t)64 * K + k0, lA + 2048);
        gload16(gB + k0, lB);
        gload16(gB + (size_t)64 * K + k0, lB + 2048);
        __syncthreads();

        short8 af[4], bf[4];
        #pragma unroll
        for (int mi = 0; mi < 4; mi++)
            af[mi] = *reinterpret_cast<const short8*>(&As[(wr * 64 + mi * 16 + lr) * 32 + lk8]);
        #pragma unroll
        for (int ni = 0; ni < 4; ni++)
            bf[ni] = *reinterpret_cast<const short8*>(&Bs[(wc * 64 + ni * 16 + lr) * 32 + lk8]);
        #pragma unroll
        for (int mi = 0; mi < 4; mi++)
            #pragma unroll
            for (int ni = 0; ni < 4; ni++)
                acc[mi][ni] = __builtin_amdgcn_mfma_f32_16x16x32_bf16(af[mi], bf[ni], acc[mi][ni], 0, 0, 0);
    }

    int org = (lane >> 4) * 4;
    if (MODE == 1) {
        #pragma unroll
        for (int mi = 0; mi < 4; mi++) {
            #pragma unroll
            for (int ni = 0; ni < 4; ni++) {
                int col = n0 + wc * 64 + ni * 16 + lr;
                float bv = bias[col];
                #pragma unroll
                for (int r = 0; r < 4; r++) {
                    int row = m0 + wr * 64 + mi * 16 + org + r;
                    outf[(size_t)row * Ndim + col] = acc[mi][ni][r] + bv;
                }
            }
        }
    } else {
        int which = n0 / 768;
        unsigned short* dst = (which == 0) ? qo : (which == 1) ? ko : vo;
        float fold = (which == 0) ? 0.125f : 1.0f;
        #pragma unroll
        for (int mi = 0; mi < 4; mi++) {
            #pragma unroll
            for (int ni = 0; ni < 4; ni++) {
                int col = n0 + wc * 64 + ni * 16 + lr;
                int rem = col - which * 768;
                int h = rem >> 6, dd = rem & 63;
                float bv = bias[col];
                #pragma unroll
                for (int r = 0; r < 4; r++) {
                    int row = m0 + wr * 64 + mi * 16 + org + r;
                    int b = row >> 10, nn = row & 1023;
                    float o = (acc[mi][ni][r] + bv) * fold;
                    dst[(((size_t)(b * H_ + h) * N_ + nn) * HD) + dd] = f2bf(o);
                }
            }
        }
    }
}

// ---------------- Flash attention: LDS-staged K/V^T, 2-phase pipeline -------
// 1D grid 1536 = 8 xcd * 12 bh * 16 qt. Block: 4 waves * 16 q-rows.
// K/V^T tiles [64][64] bf16, double-buffered, XOR-swizzled at 16B-chunk level:
// phys_chunk = logical_chunk ^ (row&7) (involution; applied on global src AND read).

__global__ __launch_bounds__(256) void attn_kernel(
    const unsigned short* __restrict__ qg,
    const unsigned short* __restrict__ kg,
    const unsigned short* __restrict__ vtg,
    unsigned short* __restrict__ aout)
{
    __shared__ alignas(16) unsigned short Ks[2][4096];
    __shared__ alignas(16) unsigned short Vs[2][4096];
    __shared__ alignas(16) unsigned short Pt[4][16][80];

    int tid = threadIdx.x;
    int lane = tid & 63, w = tid >> 6;

    int bid = blockIdx.x;
    int xcd = bid & 7;
    int chunk = bid >> 3;            // [0,192)
    int bh = xcd * 12 + (chunk % 12);
    int qt = chunk / 12;             // [0,16)
    int b = bh / H_, h = bh - b * H_;
    int q0 = qt * 64 + w * 16;
    int lr = lane & 15, lk = (lane >> 4) * 8;
    int g4 = lane >> 4;

    const unsigned short* qbase = qg + (((size_t)bh * N_) + q0) * HD;
    short8 qf0 = *reinterpret_cast<const short8*>(qbase + lr * HD + lk);
    short8 qf1 = *reinterpret_cast<const short8*>(qbase + lr * HD + lk + 32);

    const unsigned short* kbh = kg + (size_t)bh * N_ * HD;
    const unsigned short* vtbh = vtg + (size_t)bh * HD * N_;

    // staging coords: thread stages phys chunks p0=tid, p1=tid+256 of each tile
    int sr0 = tid >> 3;                 // row of chunk p0
    int sj0 = (tid & 7) ^ (sr0 & 7);    // swizzled col-chunk
    int sr1 = sr0 + 32;
    int sj1 = (tid & 7) ^ (sr1 & 7);

    float m_run[4], l_run[4];
    f32x4 o_acc[4] = {};
    #pragma unroll
    for (int r = 0; r < 4; r++) { m_run[r] = -INFINITY; l_run[r] = 0.f; }

#define STAGE(buf, kv0)                                                        \
    do {                                                                       \
        gload16(kbh + (size_t)((kv0) + sr0) * HD + sj0 * 8, &Ks[buf][w * 512]);\
        gload16(kbh + (size_t)((kv0) + sr1) * HD + sj1 * 8, &Ks[buf][2048 + w * 512]);\
        gload16(vtbh + (size_t)sr0 * N_ + (kv0) + sj0 * 8, &Vs[buf][w * 512]); \
        gload16(vtbh + (size_t)sr1 * N_ + (kv0) + sj1 * 8, &Vs[buf][2048 + w * 512]);\
    } while (0)

    STAGE(0, 0);
    asm volatile("s_waitcnt vmcnt(0)" ::: "memory");
    __builtin_amdgcn_s_barrier();
    __builtin_amdgcn_sched_barrier(0);

    int cur = 0;
    for (int t = 0; t < 16; ++t) {
        if (t < 15) STAGE(cur ^ 1, (t + 1) * 64);

        const unsigned short* Ksb = Ks[cur];
        const unsigned short* Vsb = Vs[cur];

        // S = Q K^T (swizzled reads)
        f32x4 s[4] = {};
        #pragma unroll
        for (int ct = 0; ct < 4; ct++) {
            int row = ct * 16 + lr;
            int c0 = (g4 + 0) ^ (row & 7);
            int c1 = (g4 + 4) ^ (row & 7);
            short8 kf0 = *reinterpret_cast<const short8*>(&Ksb[row * 64 + c0 * 8]);
            short8 kf1 = *reinterpret_cast<const short8*>(&Ksb[row * 64 + c1 * 8]);
            s[ct] = __builtin_amdgcn_mfma_f32_16x16x32_bf16(qf0, kf0, s[ct], 0, 0, 0);
            s[ct] = __builtin_amdgcn_mfma_f32_16x16x32_bf16(qf1, kf1, s[ct], 0, 0, 0);
        }

        // online softmax
        float mx[4], alpha[4], sm[4];
        #pragma unroll
        for (int r = 0; r < 4; r++) {
            float m = fmaxf(fmaxf(s[0][r], s[1][r]), fmaxf(s[2][r], s[3][r]));
            #pragma unroll
            for (int off = 1; off < 16; off <<= 1) m = fmaxf(m, __shfl_xor(m, off, 64));
            float mn = fmaxf(m_run[r], m);
            alpha[r] = __expf(m_run[r] - mn);
            mx[r] = mn;
            sm[r] = 0.f;
        }
        int prow = (lane >> 4) * 4;
        #pragma unroll
        for (int ct = 0; ct < 4; ct++) {
            #pragma unroll
            for (int r = 0; r < 4; r++) {
                float p = __expf(s[ct][r] - mx[r]);
                sm[r] += p;
                Pt[w][prow + r][ct * 16 + lr] = f2bf(p);
            }
        }
        #pragma unroll
        for (int r = 0; r < 4; r++) {
            float tt = sm[r];
            #pragma unroll
            for (int off = 1; off < 16; off <<= 1) tt += __shfl_xor(tt, off, 64);
            l_run[r] = l_run[r] * alpha[r] + tt;
            m_run[r] = mx[r];
        }
        #pragma unroll
        for (int ct = 0; ct < 4; ct++)
            #pragma unroll
            for (int r = 0; r < 4; r++) o_acc[ct][r] *= alpha[r];

        // O += P @ V (V^T swizzled reads)
        #pragma unroll
        for (int ks = 0; ks < 2; ks++) {
            short8 pa = *reinterpret_cast<const short8*>(&Pt[w][lr][ks * 32 + lk]);
            #pragma unroll
            for (int ct = 0; ct < 4; ct++) {
                int row = ct * 16 + lr;
                int cj = (ks * 4 + g4) ^ (row & 7);
                short8 vf = *reinterpret_cast<const short8*>(&Vsb[row * 64 + cj * 8]);
                o_acc[ct] = __builtin_amdgcn_mfma_f32_16x16x32_bf16(pa, vf, o_acc[ct], 0, 0, 0);
            }
        }

        if (t < 15) {
            asm volatile("s_waitcnt vmcnt(0)" ::: "memory");
            __builtin_amdgcn_s_barrier();
            __builtin_amdgcn_sched_barrier(0);
            cur ^= 1;
        }
    }
#undef STAGE

    int orow = (lane >> 4) * 4;
    #pragma unroll
    for (int ct = 0; ct < 4; ct++) {
        #pragma unroll
        for (int r = 0; r < 4; r++) {
            float val = o_acc[ct][r] / l_run[r];
            int n = q0 + orow + r;
            aout[((size_t)(b * N_ + n)) * D_ + h * HD + ct * 16 + lr] = f2bf(val);
        }
    }
}

// ---------------- launch ----------------

extern "C" void kernel_launch(void* const* d_in, const int* in_sizes, int n_in,
                              void* d_out, int out_size, void* d_ws, size_t ws_size,
                              hipStream_t stream) {
    const float* x      = (const float*)d_in[0];
    const float* w_qkv  = (const float*)d_in[1];
    const float* b_qkv  = (const float*)d_in[2];
    const float* w_proj = (const float*)d_in[3];
    const float* b_proj = (const float*)d_in[4];
    float* out = (float*)d_out;

    char* ws = (char*)d_ws;
    unsigned short* xb     = (unsigned short*)(ws + 0);
    unsigned short* wqkvT  = (unsigned short*)(ws + 12582912);
    unsigned short* wprojT = (unsigned short*)(ws + 16121856);
    unsigned short* qb     = (unsigned short*)(ws + 17301504);
    unsigned short* kb     = (unsigned short*)(ws + 29884416);
    unsigned short* vb     = (unsigned short*)(ws + 42467328);
    unsigned short* vtb    = (unsigned short*)(ws + 55050240);
    unsigned short* aout   = xb;  // x dead after gemm<0>

    cast_x_kernel<<<6144, 256, 0, stream>>>(x, xb, 1572864);
    transpose_cast_kernel<<<6912, 256, 0, stream>>>(w_qkv, wqkvT, 768, 2304);
    transpose_cast_kernel<<<2304, 256, 0, stream>>>(w_proj, wprojT, 768, 768);

    gemm_kernel<0><<<dim3(18, 64), 256, 0, stream>>>(
        xb, wqkvT, b_qkv, nullptr, qb, kb, vb, 3 * D_, D_);

    transpose_v_kernel<<<dim3(16, 96), 256, 0, stream>>>(vb, vtb);

    attn_kernel<<<1536, 256, 0, stream>>>(qb, kb, vtb, aout);

    gemm_kernel<1><<<dim3(6, 64), 256, 0, stream>>>(
        aout, wprojT, b_proj, out, nullptr, nullptr, nullptr, D_, D_);
}

// Round 4
// 175.240 us; speedup vs baseline: 2.4102x; 1.0988x over previous
//
#include <hip/hip_runtime.h>

#define B_ 8
#define N_ 1024
#define D_ 768
#define H_ 12
#define HD 64
#define M_ (B_*N_)

typedef short short8 __attribute__((ext_vector_type(8)));
typedef float f32x4 __attribute__((ext_vector_type(4)));

__device__ __forceinline__ unsigned short f2bf(float f) {
    union { float f; unsigned int u; } c; c.f = f;
    unsigned int u = c.u;
    unsigned int r = (u + 0x7fffu + ((u >> 16) & 1u)) >> 16;
    return (unsigned short)r;
}

// fast round-half-up (2 VALU); ties-only difference vs RNE — used for P only
__device__ __forceinline__ unsigned short f2bf_fast(float f) {
    union { float f; unsigned int u; } c; c.f = f;
    return (unsigned short)((c.u + 0x8000u) >> 16);
}

// hw 2^x (single v_exp_f32; no trans-use hazard on CDNA)
__device__ __forceinline__ float exp2_hw(float x) {
    float r;
    asm("v_exp_f32 %0, %1" : "=v"(r) : "v"(x));
    return r;
}

__device__ __forceinline__ void gload16(const void* g, void* l) {
    __builtin_amdgcn_global_load_lds(
        (const __attribute__((address_space(1))) unsigned int*)g,
        (__attribute__((address_space(3))) unsigned int*)l, 16, 0, 0);
}

// ---------------- cast / transpose kernels ----------------

__global__ void cast_x_kernel(const float* __restrict__ in,
                              unsigned short* __restrict__ out, int n4) {
    int i = blockIdx.x * blockDim.x + threadIdx.x;
    if (i >= n4) return;
    float4 v = reinterpret_cast<const float4*>(in)[i];
    ushort4 o;
    o.x = f2bf(v.x); o.y = f2bf(v.y); o.z = f2bf(v.z); o.w = f2bf(v.w);
    reinterpret_cast<ushort4*>(out)[i] = o;
}

__global__ void transpose_cast_kernel(const float* __restrict__ w,
                                      unsigned short* __restrict__ wT,
                                      int R, int C) {
    int i = blockIdx.x * blockDim.x + threadIdx.x;
    if (i >= R * C) return;
    int r = i / C, c = i - r * C;
    wT[c * R + r] = f2bf(w[i]);
}

// V [B*H][N][64] -> V^T [B*H][64][N], LDS-tiled
__global__ __launch_bounds__(256) void transpose_v_kernel(
    const unsigned short* __restrict__ vin,
    unsigned short* __restrict__ vout)
{
    __shared__ unsigned short T[64][72];
    int bh = blockIdx.y;
    int n0 = blockIdx.x * 64;
    int t = threadIdx.x;
    int r = t >> 2;
    int c = (t & 3) * 16;
    const uint4* g = reinterpret_cast<const uint4*>(vin + ((size_t)bh * N_ + n0 + r) * HD + c);
    uint4 a = g[0], b2 = g[1];
    *reinterpret_cast<uint4*>(&T[r][c]) = a;
    *reinterpret_cast<uint4*>(&T[r][c + 8]) = b2;
    __syncthreads();
    int d = t >> 2;
    int nc = (t & 3) * 16;
    unsigned short tmp[16];
    #pragma unroll
    for (int j = 0; j < 16; j++) tmp[j] = T[nc + j][d];
    uint4* o = reinterpret_cast<uint4*>(vout + ((size_t)bh * HD + d) * N_ + n0 + nc);
    o[0] = *reinterpret_cast<const uint4*>(&tmp[0]);
    o[1] = *reinterpret_cast<const uint4*>(&tmp[8]);
}

// ---------------- GEMM (m97 structure): C[M,N] = A[M,K] @ Bt[N,K]^T + bias ----

template<int MODE>
__global__ __launch_bounds__(256) void gemm_kernel(
    const unsigned short* __restrict__ A,
    const unsigned short* __restrict__ Bt,
    const float* __restrict__ bias,
    float* __restrict__ outf,
    unsigned short* __restrict__ qo,
    unsigned short* __restrict__ ko,
    unsigned short* __restrict__ vo,
    int Ndim, int K)
{
    __shared__ unsigned short As[128 * 32];
    __shared__ unsigned short Bs[128 * 32];

    int tid = threadIdx.x;
    int lane = tid & 63, w = tid >> 6;
    int wr = w >> 1, wc = w & 1;
    int m0 = blockIdx.y * 128, n0 = blockIdx.x * 128;
    int lr = lane & 15, lk8 = (lane >> 4) * 8;

    int srow = tid >> 2;
    int selem = (tid & 3) * 8;
    const unsigned short* gA = A + (size_t)(m0 + srow) * K + selem;
    const unsigned short* gB = Bt + (size_t)(n0 + srow) * K + selem;
    unsigned short* lA = As + w * 512;
    unsigned short* lB = Bs + w * 512;

    f32x4 acc[4][4] = {};

    for (int k0 = 0; k0 < K; k0 += 32) {
        __syncthreads();
        gload16(gA + k0, lA);
        gload16(gA + (size_t)64 * K + k0, lA + 2048);
        gload16(gB + k0, lB);
        gload16(gB + (size_t)64 * K + k0, lB + 2048);
        __syncthreads();

        short8 af[4], bf[4];
        #pragma unroll
        for (int mi = 0; mi < 4; mi++)
            af[mi] = *reinterpret_cast<const short8*>(&As[(wr * 64 + mi * 16 + lr) * 32 + lk8]);
        #pragma unroll
        for (int ni = 0; ni < 4; ni++)
            bf[ni] = *reinterpret_cast<const short8*>(&Bs[(wc * 64 + ni * 16 + lr) * 32 + lk8]);
        #pragma unroll
        for (int mi = 0; mi < 4; mi++)
            #pragma unroll
            for (int ni = 0; ni < 4; ni++)
                acc[mi][ni] = __builtin_amdgcn_mfma_f32_16x16x32_bf16(af[mi], bf[ni], acc[mi][ni], 0, 0, 0);
    }

    int org = (lane >> 4) * 4;
    if (MODE == 1) {
        #pragma unroll
        for (int mi = 0; mi < 4; mi++) {
            #pragma unroll
            for (int ni = 0; ni < 4; ni++) {
                int col = n0 + wc * 64 + ni * 16 + lr;
                float bv = bias[col];
                #pragma unroll
                for (int r = 0; r < 4; r++) {
                    int row = m0 + wr * 64 + mi * 16 + org + r;
                    outf[(size_t)row * Ndim + col] = acc[mi][ni][r] + bv;
                }
            }
        }
    } else {
        int which = n0 / 768;
        unsigned short* dst = (which == 0) ? qo : (which == 1) ? ko : vo;
        // q gets 1/sqrt(hd) * log2(e) folded in => attention works in exp2 domain
        float fold = (which == 0) ? 0.125f * 1.44269504088896f : 1.0f;
        #pragma unroll
        for (int mi = 0; mi < 4; mi++) {
            #pragma unroll
            for (int ni = 0; ni < 4; ni++) {
                int col = n0 + wc * 64 + ni * 16 + lr;
                int rem = col - which * 768;
                int h = rem >> 6, dd = rem & 63;
                float bv = bias[col];
                #pragma unroll
                for (int r = 0; r < 4; r++) {
                    int row = m0 + wr * 64 + mi * 16 + org + r;
                    int b = row >> 10, nn = row & 1023;
                    float o = (acc[mi][ni][r] + bv) * fold;
                    dst[(((size_t)(b * H_ + h) * N_ + nn) * HD) + dd] = f2bf(o);
                }
            }
        }
    }
}

// ---------------- Flash attention: LDS-staged K/V^T, 2-phase pipeline -------
// exp2-domain online softmax, MFMA-ones row sums, defer-max rescale.

__global__ __launch_bounds__(256) void attn_kernel(
    const unsigned short* __restrict__ qg,
    const unsigned short* __restrict__ kg,
    const unsigned short* __restrict__ vtg,
    unsigned short* __restrict__ aout)
{
    __shared__ alignas(16) unsigned short Ks[2][4096];
    __shared__ alignas(16) unsigned short Vs[2][4096];
    __shared__ alignas(16) unsigned short Pt[4][16][72];   // 144B stride: breaks g4 bank alias

    int tid = threadIdx.x;
    int lane = tid & 63, w = tid >> 6;

    int bid = blockIdx.x;
    int xcd = bid & 7;
    int chunk = bid >> 3;            // [0,192)
    int bh = xcd * 12 + (chunk % 12);
    int qt = chunk / 12;             // [0,16)
    int b = bh / H_, h = bh - b * H_;
    int q0 = qt * 64 + w * 16;
    int lr = lane & 15, lk = (lane >> 4) * 8;
    int g4 = lane >> 4;

    const unsigned short* qbase = qg + (((size_t)bh * N_) + q0) * HD;
    short8 qf0 = *reinterpret_cast<const short8*>(qbase + lr * HD + lk);
    short8 qf1 = *reinterpret_cast<const short8*>(qbase + lr * HD + lk + 32);

    const unsigned short* kbh = kg + (size_t)bh * N_ * HD;
    const unsigned short* vtbh = vtg + (size_t)bh * HD * N_;

    // bf16 1.0 fragment for MFMA row-sum
    short8 ones;
    #pragma unroll
    for (int j = 0; j < 8; j++) ones[j] = (short)0x3F80;

    // staging coords: thread stages phys chunks p0=tid, p1=tid+256 of each tile
    int sr0 = tid >> 3;
    int sj0 = (tid & 7) ^ (sr0 & 7);
    int sr1 = sr0 + 32;
    int sj1 = (tid & 7) ^ (sr1 & 7);

    float m_run[4], l_run[4];
    f32x4 o_acc[4] = {};
    #pragma unroll
    for (int r = 0; r < 4; r++) { m_run[r] = -INFINITY; l_run[r] = 0.f; }

#define STAGE(buf, kv0)                                                        \
    do {                                                                       \
        gload16(kbh + (size_t)((kv0) + sr0) * HD + sj0 * 8, &Ks[buf][w * 512]);\
        gload16(kbh + (size_t)((kv0) + sr1) * HD + sj1 * 8, &Ks[buf][2048 + w * 512]);\
        gload16(vtbh + (size_t)sr0 * N_ + (kv0) + sj0 * 8, &Vs[buf][w * 512]); \
        gload16(vtbh + (size_t)sr1 * N_ + (kv0) + sj1 * 8, &Vs[buf][2048 + w * 512]);\
    } while (0)

    STAGE(0, 0);
    asm volatile("s_waitcnt vmcnt(0)" ::: "memory");
    __builtin_amdgcn_s_barrier();
    __builtin_amdgcn_sched_barrier(0);

    int cur = 0;
    for (int t = 0; t < 16; ++t) {
        if (t < 15) STAGE(cur ^ 1, (t + 1) * 64);

        const unsigned short* Ksb = Ks[cur];
        const unsigned short* Vsb = Vs[cur];

        // S = Q K^T (swizzled reads); S already in log2 domain (log2e folded into q)
        f32x4 s[4] = {};
        #pragma unroll
        for (int ct = 0; ct < 4; ct++) {
            int row = ct * 16 + lr;
            int c0 = (g4 + 0) ^ (row & 7);
            int c1 = (g4 + 4) ^ (row & 7);
            short8 kf0 = *reinterpret_cast<const short8*>(&Ksb[row * 64 + c0 * 8]);
            short8 kf1 = *reinterpret_cast<const short8*>(&Ksb[row * 64 + c1 * 8]);
            s[ct] = __builtin_amdgcn_mfma_f32_16x16x32_bf16(qf0, kf0, s[ct], 0, 0, 0);
            s[ct] = __builtin_amdgcn_mfma_f32_16x16x32_bf16(qf1, kf1, s[ct], 0, 0, 0);
        }

        // row max (4-step 16-lane butterfly)
        float mx[4];
        bool resc = false;
        #pragma unroll
        for (int r = 0; r < 4; r++) {
            float m = fmaxf(fmaxf(s[0][r], s[1][r]), fmaxf(s[2][r], s[3][r]));
            #pragma unroll
            for (int off = 1; off < 16; off <<= 1) m = fmaxf(m, __shfl_xor(m, off, 64));
            mx[r] = m;
            resc |= (m > m_run[r] + 8.f);
        }
        // defer-max: only rescale when max grew past threshold (wave-uniform branch)
        if (__any(resc)) {
            #pragma unroll
            for (int r = 0; r < 4; r++) {
                float mn = fmaxf(m_run[r], mx[r]);
                float al = exp2_hw(m_run[r] - mn);
                m_run[r] = mn;
                l_run[r] *= al;
                #pragma unroll
                for (int ct = 0; ct < 4; ct++) o_acc[ct][r] *= al;
            }
        }

        // P = exp2(S - m), bf16 to per-wave LDS
        int prow = g4 * 4;
        #pragma unroll
        for (int ct = 0; ct < 4; ct++) {
            #pragma unroll
            for (int r = 0; r < 4; r++) {
                float p = exp2_hw(s[ct][r] - m_run[r]);
                Pt[w][prow + r][ct * 16 + lr] = f2bf_fast(p);
            }
        }

        // O += P @ V ; row-sums via MFMA with ones-B (replaces shuffle-sum)
        f32x4 lsum = {};
        #pragma unroll
        for (int ks = 0; ks < 2; ks++) {
            short8 pa = *reinterpret_cast<const short8*>(&Pt[w][lr][ks * 32 + lk]);
            lsum = __builtin_amdgcn_mfma_f32_16x16x32_bf16(pa, ones, lsum, 0, 0, 0);
            #pragma unroll
            for (int ct = 0; ct < 4; ct++) {
                int row = ct * 16 + lr;
                int cj = (ks * 4 + g4) ^ (row & 7);
                short8 vf = *reinterpret_cast<const short8*>(&Vsb[row * 64 + cj * 8]);
                o_acc[ct] = __builtin_amdgcn_mfma_f32_16x16x32_bf16(pa, vf, o_acc[ct], 0, 0, 0);
            }
        }
        #pragma unroll
        for (int r = 0; r < 4; r++) l_run[r] += lsum[r];

        if (t < 15) {
            asm volatile("s_waitcnt vmcnt(0)" ::: "memory");
            __builtin_amdgcn_s_barrier();
            __builtin_amdgcn_sched_barrier(0);
            cur ^= 1;
        }
    }
#undef STAGE

    int orow = g4 * 4;
    #pragma unroll
    for (int ct = 0; ct < 4; ct++) {
        #pragma unroll
        for (int r = 0; r < 4; r++) {
            float val = o_acc[ct][r] / l_run[r];
            int n = q0 + orow + r;
            aout[((size_t)(b * N_ + n)) * D_ + h * HD + ct * 16 + lr] = f2bf(val);
        }
    }
}

// ---------------- launch ----------------

extern "C" void kernel_launch(void* const* d_in, const int* in_sizes, int n_in,
                              void* d_out, int out_size, void* d_ws, size_t ws_size,
                              hipStream_t stream) {
    const float* x      = (const float*)d_in[0];
    const float* w_qkv  = (const float*)d_in[1];
    const float* b_qkv  = (const float*)d_in[2];
    const float* w_proj = (const float*)d_in[3];
    const float* b_proj = (const float*)d_in[4];
    float* out = (float*)d_out;

    char* ws = (char*)d_ws;
    unsigned short* xb     = (unsigned short*)(ws + 0);
    unsigned short* wqkvT  = (unsigned short*)(ws + 12582912);
    unsigned short* wprojT = (unsigned short*)(ws + 16121856);
    unsigned short* qb     = (unsigned short*)(ws + 17301504);
    unsigned short* kb     = (unsigned short*)(ws + 29884416);
    unsigned short* vb     = (unsigned short*)(ws + 42467328);
    unsigned short* vtb    = (unsigned short*)(ws + 55050240);
    unsigned short* aout   = xb;  // x dead after gemm<0>

    cast_x_kernel<<<6144, 256, 0, stream>>>(x, xb, 1572864);
    transpose_cast_kernel<<<6912, 256, 0, stream>>>(w_qkv, wqkvT, 768, 2304);
    transpose_cast_kernel<<<2304, 256, 0, stream>>>(w_proj, wprojT, 768, 768);

    gemm_kernel<0><<<dim3(18, 64), 256, 0, stream>>>(
        xb, wqkvT, b_qkv, nullptr, qb, kb, vb, 3 * D_, D_);

    transpose_v_kernel<<<dim3(16, 96), 256, 0, stream>>>(vb, vtb);

    attn_kernel<<<1536, 256, 0, stream>>>(qb, kb, vtb, aout);

    gemm_kernel<1><<<dim3(6, 64), 256, 0, stream>>>(
        aout, wprojT, b_proj, out, nullptr, nullptr, nullptr, D_, D_);
}

// Round 6
// 148.318 us; speedup vs baseline: 2.8477x; 1.1815x over previous
//
#include <hip/hip_runtime.h>

#define B_ 8
#define N_ 1024
#define D_ 768
#define H_ 12
#define HD 64
#define M_ (B_*N_)

typedef short short8 __attribute__((ext_vector_type(8)));
typedef float f32x4 __attribute__((ext_vector_type(4)));
typedef float f32x16 __attribute__((ext_vector_type(16)));
typedef int int4v __attribute__((ext_vector_type(4)));

__device__ __forceinline__ unsigned short f2bf(float f) {
    union { float f; unsigned int u; } c; c.f = f;
    unsigned int u = c.u;
    unsigned int r = (u + 0x7fffu + ((u >> 16) & 1u)) >> 16;
    return (unsigned short)r;
}

// hw 2^x (single v_exp_f32)
__device__ __forceinline__ float exp2_hw(float x) {
    float r;
    asm("v_exp_f32 %0, %1" : "=v"(r) : "v"(x));
    return r;
}

// pack two f32 -> one u32 of 2 bf16 (RNE), low word = a
__device__ __forceinline__ unsigned int cvtpk_bf16(float a, float b) {
    unsigned int r;
    asm("v_cvt_pk_bf16_f32 %0, %1, %2" : "=v"(r) : "v"(a), "v"(b));
    return r;
}

// swap a's lanes32-63 with b's lanes0-31.
// "+&v" early-clobber on BOTH: forces distinct VGPRs (with plain "+v" the
// allocator may coalesce equal-valued operands into one register, turning the
// swap into a single-register half-rotate — round-5 bug).
#define PLSWAP(a, b) asm volatile("v_permlane32_swap_b32 %0, %1" : "+&v"(a), "+&v"(b))

__device__ __forceinline__ short8 pack4(unsigned int a, unsigned int b,
                                        unsigned int c, unsigned int d) {
    union { int4v i; short8 s; } u;
    u.i = (int4v){(int)a, (int)b, (int)c, (int)d};
    return u.s;
}

__device__ __forceinline__ void gload16(const void* g, void* l) {
    __builtin_amdgcn_global_load_lds(
        (const __attribute__((address_space(1))) unsigned int*)g,
        (__attribute__((address_space(3))) unsigned int*)l, 16, 0, 0);
}

// ---------------- cast / transpose kernels ----------------

__global__ void cast_x_kernel(const float* __restrict__ in,
                              unsigned short* __restrict__ out, int n4) {
    int i = blockIdx.x * blockDim.x + threadIdx.x;
    if (i >= n4) return;
    float4 v = reinterpret_cast<const float4*>(in)[i];
    ushort4 o;
    o.x = f2bf(v.x); o.y = f2bf(v.y); o.z = f2bf(v.z); o.w = f2bf(v.w);
    reinterpret_cast<ushort4*>(out)[i] = o;
}

__global__ void transpose_cast_kernel(const float* __restrict__ w,
                                      unsigned short* __restrict__ wT,
                                      int R, int C) {
    int i = blockIdx.x * blockDim.x + threadIdx.x;
    if (i >= R * C) return;
    int r = i / C, c = i - r * C;
    wT[c * R + r] = f2bf(w[i]);
}

// V [B*H][N][64] -> V^T [B*H][64][N], LDS-tiled
__global__ __launch_bounds__(256) void transpose_v_kernel(
    const unsigned short* __restrict__ vin,
    unsigned short* __restrict__ vout)
{
    __shared__ unsigned short T[64][72];
    int bh = blockIdx.y;
    int n0 = blockIdx.x * 64;
    int t = threadIdx.x;
    int r = t >> 2;
    int c = (t & 3) * 16;
    const uint4* g = reinterpret_cast<const uint4*>(vin + ((size_t)bh * N_ + n0 + r) * HD + c);
    uint4 a = g[0], b2 = g[1];
    *reinterpret_cast<uint4*>(&T[r][c]) = a;
    *reinterpret_cast<uint4*>(&T[r][c + 8]) = b2;
    __syncthreads();
    int d = t >> 2;
    int nc = (t & 3) * 16;
    unsigned short tmp[16];
    #pragma unroll
    for (int j = 0; j < 16; j++) tmp[j] = T[nc + j][d];
    uint4* o = reinterpret_cast<uint4*>(vout + ((size_t)bh * HD + d) * N_ + n0 + nc);
    o[0] = *reinterpret_cast<const uint4*>(&tmp[0]);
    o[1] = *reinterpret_cast<const uint4*>(&tmp[8]);
}

// ---------------- GEMM (m97 structure): C[M,N] = A[M,K] @ Bt[N,K]^T + bias ----

template<int MODE>
__global__ __launch_bounds__(256) void gemm_kernel(
    const unsigned short* __restrict__ A,
    const unsigned short* __restrict__ Bt,
    const float* __restrict__ bias,
    float* __restrict__ outf,
    unsigned short* __restrict__ qo,
    unsigned short* __restrict__ ko,
    unsigned short* __restrict__ vo,
    int Ndim, int K)
{
    __shared__ unsigned short As[128 * 32];
    __shared__ unsigned short Bs[128 * 32];

    int tid = threadIdx.x;
    int lane = tid & 63, w = tid >> 6;
    int wr = w >> 1, wc = w & 1;
    int m0 = blockIdx.y * 128, n0 = blockIdx.x * 128;
    int lr = lane & 15, lk8 = (lane >> 4) * 8;

    int srow = tid >> 2;
    int selem = (tid & 3) * 8;
    const unsigned short* gA = A + (size_t)(m0 + srow) * K + selem;
    const unsigned short* gB = Bt + (size_t)(n0 + srow) * K + selem;
    unsigned short* lA = As + w * 512;
    unsigned short* lB = Bs + w * 512;

    f32x4 acc[4][4] = {};

    for (int k0 = 0; k0 < K; k0 += 32) {
        __syncthreads();
        gload16(gA + k0, lA);
        gload16(gA + (size_t)64 * K + k0, lA + 2048);
        gload16(gB + k0, lB);
        gload16(gB + (size_t)64 * K + k0, lB + 2048);
        __syncthreads();

        short8 af[4], bf[4];
        #pragma unroll
        for (int mi = 0; mi < 4; mi++)
            af[mi] = *reinterpret_cast<const short8*>(&As[(wr * 64 + mi * 16 + lr) * 32 + lk8]);
        #pragma unroll
        for (int ni = 0; ni < 4; ni++)
            bf[ni] = *reinterpret_cast<const short8*>(&Bs[(wc * 64 + ni * 16 + lr) * 32 + lk8]);
        #pragma unroll
        for (int mi = 0; mi < 4; mi++)
            #pragma unroll
            for (int ni = 0; ni < 4; ni++)
                acc[mi][ni] = __builtin_amdgcn_mfma_f32_16x16x32_bf16(af[mi], bf[ni], acc[mi][ni], 0, 0, 0);
    }

    int org = (lane >> 4) * 4;
    if (MODE == 1) {
        #pragma unroll
        for (int mi = 0; mi < 4; mi++) {
            #pragma unroll
            for (int ni = 0; ni < 4; ni++) {
                int col = n0 + wc * 64 + ni * 16 + lr;
                float bv = bias[col];
                #pragma unroll
                for (int r = 0; r < 4; r++) {
                    int row = m0 + wr * 64 + mi * 16 + org + r;
                    outf[(size_t)row * Ndim + col] = acc[mi][ni][r] + bv;
                }
            }
        }
    } else {
        int which = n0 / 768;
        unsigned short* dst = (which == 0) ? qo : (which == 1) ? ko : vo;
        // q gets 1/sqrt(hd) * log2(e) folded in => attention works in exp2 domain
        float fold = (which == 0) ? 0.125f * 1.44269504088896f : 1.0f;
        #pragma unroll
        for (int mi = 0; mi < 4; mi++) {
            #pragma unroll
            for (int ni = 0; ni < 4; ni++) {
                int col = n0 + wc * 64 + ni * 16 + lr;
                int rem = col - which * 768;
                int h = rem >> 6, dd = rem & 63;
                float bv = bias[col];
                #pragma unroll
                for (int r = 0; r < 4; r++) {
                    int row = m0 + wr * 64 + mi * 16 + org + r;
                    int b = row >> 10, nn = row & 1023;
                    float o = (acc[mi][ni][r] + bv) * fold;
                    dst[(((size_t)(b * H_ + h) * N_ + nn) * HD) + dd] = f2bf(o);
                }
            }
        }
    }
}

// ---------------- Flash attention: swapped-operand 32x32 MFMA, in-register P
// grid 768 = 8 xcd * 12 bh * 8 qblk. Block: 4 waves, each owns 32 q-rows.
// S^T = mfma(K, Q): lane q=lane&31 holds S[q][k], k = sub*32+(reg&3)+8*(reg>>2)+4*hi.
// O^T = mfma(V^T, P^T): P^T B-frags built in-register via cvt_pk + permlane32_swap.

__global__ __launch_bounds__(256) void attn_kernel(
    const unsigned short* __restrict__ qg,
    const unsigned short* __restrict__ kg,
    const unsigned short* __restrict__ vtg,
    unsigned short* __restrict__ aout)
{
    __shared__ alignas(16) unsigned short Ks[2][4096];
    __shared__ alignas(16) unsigned short Vs[2][4096];

    int tid = threadIdx.x;
    int lane = tid & 63, w = tid >> 6;

    int bid = blockIdx.x;
    int xcd = bid & 7;
    int chunk = bid >> 3;            // [0,96)
    int bh = xcd * 12 + (chunk % 12);
    int qblk = chunk / 12;           // [0,8)
    int b = bh / H_, h = bh - b * H_;
    int q0w = qblk * 128 + w * 32;
    int l31 = lane & 31;
    int hi = lane >> 5;
    int swz = l31 & 7;               // read-side XOR swizzle key (row&7; rows l31 and 32+l31 share it)

    // Q B-frags: qf[ds] = Q[q0w+l31][ds*16 + hi*8 + 0..7]
    const unsigned short* qp = qg + ((size_t)bh * N_ + q0w + l31) * HD + hi * 8;
    short8 qf[4];
    #pragma unroll
    for (int ds = 0; ds < 4; ds++)
        qf[ds] = *reinterpret_cast<const short8*>(qp + ds * 16);

    const unsigned short* kbh = kg + (size_t)bh * N_ * HD;
    const unsigned short* vtbh = vtg + (size_t)bh * HD * N_;

    // staging coords (inverse-swizzled global source, linear LDS dest)
    int sr0 = tid >> 3;
    int sj0 = (tid & 7) ^ (sr0 & 7);
    int sr1 = sr0 + 32;
    int sj1 = (tid & 7) ^ (sr1 & 7);

    float m_run = -INFINITY, l_run = 0.f;
    f32x16 o0 = {}, o1 = {};

#define STAGE(buf, kv0)                                                        \
    do {                                                                       \
        gload16(kbh + (size_t)((kv0) + sr0) * HD + sj0 * 8, &Ks[buf][w * 512]);\
        gload16(kbh + (size_t)((kv0) + sr1) * HD + sj1 * 8, &Ks[buf][2048 + w * 512]);\
        gload16(vtbh + (size_t)sr0 * N_ + (kv0) + sj0 * 8, &Vs[buf][w * 512]); \
        gload16(vtbh + (size_t)sr1 * N_ + (kv0) + sj1 * 8, &Vs[buf][2048 + w * 512]);\
    } while (0)

    STAGE(0, 0);
    asm volatile("s_waitcnt vmcnt(0)" ::: "memory");
    __builtin_amdgcn_s_barrier();
    __builtin_amdgcn_sched_barrier(0);

    int cur = 0;
    for (int t = 0; t < 16; ++t) {
        if (t < 15) STAGE(cur ^ 1, (t + 1) * 64);

        const unsigned short* Ksb = Ks[cur];
        const unsigned short* Vsb = Vs[cur];

        // S^T = K * Q  (two 32k x 32q subtiles)
        f32x16 s0 = {}, s1 = {};
        #pragma unroll
        for (int ds = 0; ds < 4; ds++) {
            int pc = (ds * 2 + hi) ^ swz;
            short8 kf0 = *reinterpret_cast<const short8*>(&Ksb[(l31) * 64 + pc * 8]);
            short8 kf1 = *reinterpret_cast<const short8*>(&Ksb[(32 + l31) * 64 + pc * 8]);
            s0 = __builtin_amdgcn_mfma_f32_32x32x16_bf16(kf0, qf[ds], s0, 0, 0, 0);
            s1 = __builtin_amdgcn_mfma_f32_32x32x16_bf16(kf1, qf[ds], s1, 0, 0, 0);
        }

        // row max over lane's 32 values, then alias-proof cross-half combine
        float mx = s0[0];
        #pragma unroll
        for (int r = 1; r < 16; r++) mx = fmaxf(mx, s0[r]);
        #pragma unroll
        for (int r = 0; r < 16; r++) mx = fmaxf(mx, s1[r]);
        mx = fmaxf(mx, __shfl_xor(mx, 32, 64));

        // defer-max rescale (wave-uniform branch)
        if (__any(mx > m_run + 8.f)) {
            float mn = fmaxf(m_run, mx);
            float al = exp2_hw(m_run - mn);
            m_run = mn;
            l_run *= al;
            o0 *= al;
            o1 *= al;
        }

        // P = exp2(S - m), accumulate lane-partial row sum
        float psum = 0.f;
        #pragma unroll
        for (int r = 0; r < 16; r++) { float p = exp2_hw(s0[r] - m_run); psum += p; s0[r] = p; }
        #pragma unroll
        for (int r = 0; r < 16; r++) { float p = exp2_hw(s1[r] - m_run); psum += p; s1[r] = p; }

        // full row sum across halves (alias-proof)
        l_run += psum + __shfl_xor(psum, 32, 64);

        // pack to bf16 pairs (consecutive k), redistribute across halves
        unsigned int c0[8], c1[8];
        #pragma unroll
        for (int i = 0; i < 8; i++) c0[i] = cvtpk_bf16(s0[2 * i], s0[2 * i + 1]);
        #pragma unroll
        for (int i = 0; i < 8; i++) c1[i] = cvtpk_bf16(s1[2 * i], s1[2 * i + 1]);
        PLSWAP(c0[0], c0[2]); PLSWAP(c0[1], c0[3]);
        PLSWAP(c0[4], c0[6]); PLSWAP(c0[5], c0[7]);
        PLSWAP(c1[0], c1[2]); PLSWAP(c1[1], c1[3]);
        PLSWAP(c1[4], c1[6]); PLSWAP(c1[5], c1[7]);
        short8 pa0 = pack4(c0[0], c0[1], c0[2], c0[3]);
        short8 pa1 = pack4(c0[4], c0[5], c0[6], c0[7]);
        short8 pa2 = pack4(c1[0], c1[1], c1[2], c1[3]);
        short8 pa3 = pack4(c1[4], c1[5], c1[6], c1[7]);

        // O^T += V^T * P^T  (two 32d subtiles x 4 k-steps)
        #pragma unroll
        for (int ks = 0; ks < 4; ks++) {
            int pc = (ks * 2 + hi) ^ swz;
            short8 vf0 = *reinterpret_cast<const short8*>(&Vsb[(l31) * 64 + pc * 8]);
            short8 vf1 = *reinterpret_cast<const short8*>(&Vsb[(32 + l31) * 64 + pc * 8]);
            short8 pa = (ks == 0) ? pa0 : (ks == 1) ? pa1 : (ks == 2) ? pa2 : pa3;
            o0 = __builtin_amdgcn_mfma_f32_32x32x16_bf16(vf0, pa, o0, 0, 0, 0);
            o1 = __builtin_amdgcn_mfma_f32_32x32x16_bf16(vf1, pa, o1, 0, 0, 0);
        }

        if (t < 15) {
            asm volatile("s_waitcnt vmcnt(0)" ::: "memory");
            __builtin_amdgcn_s_barrier();
            __builtin_amdgcn_sched_barrier(0);
            cur ^= 1;
        }
    }
#undef STAGE

    // epilogue: lane writes q = q0w+l31, d in {8*rg + 4*hi + 0..3} (+32 for o1)
    float linv = 1.0f / l_run;
    unsigned short* op = aout + ((size_t)(b * N_ + q0w + l31)) * D_ + h * HD;
    #pragma unroll
    for (int rg = 0; rg < 4; rg++) {
        int dbase = 8 * rg + 4 * hi;
        unsigned long long u0 = 0, u1 = 0;
        #pragma unroll
        for (int k = 0; k < 4; k++) {
            u0 |= (unsigned long long)f2bf(o0[rg * 4 + k] * linv) << (16 * k);
            u1 |= (unsigned long long)f2bf(o1[rg * 4 + k] * linv) << (16 * k);
        }
        *reinterpret_cast<unsigned long long*>(op + dbase) = u0;
        *reinterpret_cast<unsigned long long*>(op + 32 + dbase) = u1;
    }
}

// ---------------- launch ----------------

extern "C" void kernel_launch(void* const* d_in, const int* in_sizes, int n_in,
                              void* d_out, int out_size, void* d_ws, size_t ws_size,
                              hipStream_t stream) {
    const float* x      = (const float*)d_in[0];
    const float* w_qkv  = (const float*)d_in[1];
    const float* b_qkv  = (const float*)d_in[2];
    const float* w_proj = (const float*)d_in[3];
    const float* b_proj = (const float*)d_in[4];
    float* out = (float*)d_out;

    char* ws = (char*)d_ws;
    unsigned short* xb     = (unsigned short*)(ws + 0);
    unsigned short* wqkvT  = (unsigned short*)(ws + 12582912);
    unsigned short* wprojT = (unsigned short*)(ws + 16121856);
    unsigned short* qb     = (unsigned short*)(ws + 17301504);
    unsigned short* kb     = (unsigned short*)(ws + 29884416);
    unsigned short* vb     = (unsigned short*)(ws + 42467328);
    unsigned short* vtb    = (unsigned short*)(ws + 55050240);
    unsigned short* aout   = xb;  // x dead after gemm<0>

    cast_x_kernel<<<6144, 256, 0, stream>>>(x, xb, 1572864);
    transpose_cast_kernel<<<6912, 256, 0, stream>>>(w_qkv, wqkvT, 768, 2304);
    transpose_cast_kernel<<<2304, 256, 0, stream>>>(w_proj, wprojT, 768, 768);

    gemm_kernel<0><<<dim3(18, 64), 256, 0, stream>>>(
        xb, wqkvT, b_qkv, nullptr, qb, kb, vb, 3 * D_, D_);

    transpose_v_kernel<<<dim3(16, 96), 256, 0, stream>>>(vb, vtb);

    attn_kernel<<<768, 256, 0, stream>>>(qb, kb, vtb, aout);

    gemm_kernel<1><<<dim3(6, 64), 256, 0, stream>>>(
        aout, wprojT, b_proj, out, nullptr, nullptr, nullptr, D_, D_);
}

// Round 7
// 136.174 us; speedup vs baseline: 3.1016x; 1.0892x over previous
//
#include <hip/hip_runtime.h>

#define B_ 8
#define N_ 1024
#define D_ 768
#define H_ 12
#define HD 64
#define M_ (B_*N_)

typedef short short8 __attribute__((ext_vector_type(8)));
typedef float f32x4 __attribute__((ext_vector_type(4)));
typedef float f32x16 __attribute__((ext_vector_type(16)));
typedef int int4v __attribute__((ext_vector_type(4)));

__device__ __forceinline__ unsigned short f2bf(float f) {
    union { float f; unsigned int u; } c; c.f = f;
    unsigned int u = c.u;
    unsigned int r = (u + 0x7fffu + ((u >> 16) & 1u)) >> 16;
    return (unsigned short)r;
}

__device__ __forceinline__ float exp2_hw(float x) {
    float r;
    asm("v_exp_f32 %0, %1" : "=v"(r) : "v"(x));
    return r;
}

__device__ __forceinline__ unsigned int cvtpk_bf16(float a, float b) {
    unsigned int r;
    asm("v_cvt_pk_bf16_f32 %0, %1, %2" : "=v"(r) : "v"(a), "v"(b));
    return r;
}

// swap a's lanes32-63 with b's lanes0-31. "+&v" early-clobber forces distinct
// VGPRs (plain "+v" lets the allocator coalesce equal-valued operands — r5 bug).
#define PLSWAP(a, b) asm volatile("v_permlane32_swap_b32 %0, %1" : "+&v"(a), "+&v"(b))

__device__ __forceinline__ short8 pack4(unsigned int a, unsigned int b,
                                        unsigned int c, unsigned int d) {
    union { int4v i; short8 s; } u;
    u.i = (int4v){(int)a, (int)b, (int)c, (int)d};
    return u.s;
}

__device__ __forceinline__ void gload16(const void* g, void* l) {
    __builtin_amdgcn_global_load_lds(
        (const __attribute__((address_space(1))) unsigned int*)g,
        (__attribute__((address_space(3))) unsigned int*)l, 16, 0, 0);
}

// ---------------- fused prep: cast x, transpose+cast both weights ----------

__global__ __launch_bounds__(256) void prep_kernel(
    const float* __restrict__ x, const float* __restrict__ wqkv,
    const float* __restrict__ wproj,
    unsigned short* __restrict__ xb, unsigned short* __restrict__ wqkvT,
    unsigned short* __restrict__ wprojT)
{
    int bid = blockIdx.x, tid = threadIdx.x;
    if (bid < 6144) {
        int i = bid * 256 + tid;
        float4 v = reinterpret_cast<const float4*>(x)[i];
        ushort4 o;
        o.x = f2bf(v.x); o.y = f2bf(v.y); o.z = f2bf(v.z); o.w = f2bf(v.w);
        reinterpret_cast<ushort4*>(xb)[i] = o;
    } else if (bid < 6144 + 6912) {
        int i = (bid - 6144) * 256 + tid;
        int r = i / 2304, c = i - r * 2304;
        wqkvT[c * 768 + r] = f2bf(wqkv[i]);
    } else {
        int i = (bid - 13056) * 256 + tid;
        int r = i / 768, c = i - r * 768;
        wprojT[c * 768 + r] = f2bf(wproj[i]);
    }
}

// ---------------- GEMM: 2-phase pipelined, XCD-chunked, coalesced epilogue --
// C[M,N] = A[M,K] @ Bt[N,K]^T + bias. 128x128 tile, BK=32, 4 waves (2x2).
// MODE 0: q/k -> [B,H,N,hd] (LDS-bounce coalesced), v -> vt [B,H,hd,N] (direct)
// MODE 1: fp32 scatter to outf [M,N]

template<int MODE>
__global__ __launch_bounds__(256) void gemm_kernel(
    const unsigned short* __restrict__ A,
    const unsigned short* __restrict__ Bt,
    const float* __restrict__ bias,
    float* __restrict__ outf,
    unsigned short* __restrict__ qo,
    unsigned short* __restrict__ ko,
    unsigned short* __restrict__ vo,
    int Ndim, int K)
{
    __shared__ alignas(16) unsigned short smem[16384];   // 32 KB
    unsigned short* As0 = smem;          // [2][4096]
    unsigned short* Bs0 = smem + 8192;   // [2][4096]

    int tid = threadIdx.x;
    int lane = tid & 63, w = tid >> 6;
    int wr = w >> 1, wc = w & 1;

    // XCD-chunked 1D grid: each XCD gets 8 contiguous row-panels
    int nbx = Ndim >> 7;
    int nwg = gridDim.x;                 // multiple of 8
    int cpx = nwg >> 3;
    int sbid = (blockIdx.x & 7) * cpx + (blockIdx.x >> 3);
    int bx = sbid % nbx, by = sbid / nbx;
    int m0 = by * 128, n0 = bx * 128;

    int lr = lane & 15, lk8 = (lane >> 4) * 8;
    int org = (lane >> 4) * 4;

    int srow = tid >> 2;
    int selem = (tid & 3) * 8;
    const unsigned short* gA = A + (size_t)(m0 + srow) * K + selem;
    const unsigned short* gB = Bt + (size_t)(n0 + srow) * K + selem;

    f32x4 acc[4][4] = {};

#define GSTAGE(buf, k0)                                                    \
    do {                                                                   \
        gload16(gA + (k0), As0 + (buf) * 4096 + w * 512);                  \
        gload16(gA + (size_t)64 * K + (k0), As0 + (buf) * 4096 + 2048 + w * 512);\
        gload16(gB + (k0), Bs0 + (buf) * 4096 + w * 512);                  \
        gload16(gB + (size_t)64 * K + (k0), Bs0 + (buf) * 4096 + 2048 + w * 512);\
    } while (0)

    GSTAGE(0, 0);
    asm volatile("s_waitcnt vmcnt(0)" ::: "memory");
    __builtin_amdgcn_s_barrier();
    __builtin_amdgcn_sched_barrier(0);

    int KT = K >> 5;
    int cur = 0;
    for (int kt = 0; kt < KT; ++kt) {
        if (kt + 1 < KT) GSTAGE(cur ^ 1, (kt + 1) * 32);

        const unsigned short* Ab = As0 + cur * 4096;
        const unsigned short* Bb = Bs0 + cur * 4096;
        short8 af[4], bf[4];
        #pragma unroll
        for (int mi = 0; mi < 4; mi++)
            af[mi] = *reinterpret_cast<const short8*>(&Ab[(wr * 64 + mi * 16 + lr) * 32 + lk8]);
        #pragma unroll
        for (int ni = 0; ni < 4; ni++)
            bf[ni] = *reinterpret_cast<const short8*>(&Bb[(wc * 64 + ni * 16 + lr) * 32 + lk8]);
        #pragma unroll
        for (int mi = 0; mi < 4; mi++)
            #pragma unroll
            for (int ni = 0; ni < 4; ni++)
                acc[mi][ni] = __builtin_amdgcn_mfma_f32_16x16x32_bf16(af[mi], bf[ni], acc[mi][ni], 0, 0, 0);

        if (kt + 1 < KT) {
            asm volatile("s_waitcnt vmcnt(0)" ::: "memory");
            __builtin_amdgcn_s_barrier();
            __builtin_amdgcn_sched_barrier(0);
            cur ^= 1;
        }
    }
#undef GSTAGE

    if (MODE == 1) {
        #pragma unroll
        for (int mi = 0; mi < 4; mi++) {
            #pragma unroll
            for (int ni = 0; ni < 4; ni++) {
                int col = n0 + wc * 64 + ni * 16 + lr;
                float bv = bias[col];
                #pragma unroll
                for (int r = 0; r < 4; r++) {
                    int row = m0 + wr * 64 + mi * 16 + org + r;
                    outf[(size_t)row * Ndim + col] = acc[mi][ni][r] + bv;
                }
            }
        }
        return;
    }

    int which = n0 / 768;
    if (which == 2) {
        // v: write directly transposed into vt[B,H,hd,N] — 8B contiguous stores
        #pragma unroll
        for (int mi = 0; mi < 4; mi++) {
            int nn0g = m0 + wr * 64 + mi * 16 + org;
            int b = nn0g >> 10, nn = nn0g & 1023;
            #pragma unroll
            for (int ni = 0; ni < 4; ni++) {
                int colg = n0 + wc * 64 + ni * 16 + lr;
                int rem = colg - 1536;
                int h = rem >> 6, dd = rem & 63;
                float bv = bias[colg];
                unsigned long long u = 0;
                #pragma unroll
                for (int r = 0; r < 4; r++)
                    u |= (unsigned long long)f2bf(acc[mi][ni][r] + bv) << (16 * r);
                *reinterpret_cast<unsigned long long*>(
                    vo + ((size_t)(b * H_ + h) * HD + dd) * N_ + nn) = u;
            }
        }
    } else {
        // q/k: LDS-bounce to coalesced row-major [B,H,N,hd] writes
        unsigned short* dst = (which == 0) ? qo : ko;
        float fold = (which == 0) ? 0.125f * 1.44269504088896f : 1.0f; // scale*log2e into q
        unsigned short* T = smem;   // reuse: 128 x 72 bf16 = 18 KB
        __syncthreads();            // all K-loop ds_reads done before overwrite
        #pragma unroll
        for (int hc = 0; hc < 2; ++hc) {
            if (hc) __syncthreads();
            if (wc == hc) {
                #pragma unroll
                for (int mi = 0; mi < 4; mi++) {
                    int rl = wr * 64 + mi * 16 + org;
                    #pragma unroll
                    for (int ni = 0; ni < 4; ni++) {
                        int cl = ni * 16 + lr;
                        float bv = bias[n0 + hc * 64 + cl];
                        #pragma unroll
                        for (int r = 0; r < 4; r++)
                            T[(rl + r) * 72 + cl] = f2bf((acc[mi][ni][r] + bv) * fold);
                    }
                }
            }
            __syncthreads();
            int row = tid >> 1, c0 = (tid & 1) * 32;
            int h = (n0 + hc * 64 - which * 768) >> 6;
            int nng = m0 + row;
            int b = nng >> 10, nn = nng & 1023;
            const uint4* src = reinterpret_cast<const uint4*>(&T[row * 72 + c0]);
            uint4* dv = reinterpret_cast<uint4*>(dst + ((size_t)(b * H_ + h) * N_ + nn) * HD + c0);
            dv[0] = src[0]; dv[1] = src[1]; dv[2] = src[2]; dv[3] = src[3];
        }
    }
}

// ---------------- Flash attention: swapped-operand 32x32 MFMA, in-register P
// (unchanged from round 6 — passing at absmax 2.2e-3)

__global__ __launch_bounds__(256) void attn_kernel(
    const unsigned short* __restrict__ qg,
    const unsigned short* __restrict__ kg,
    const unsigned short* __restrict__ vtg,
    unsigned short* __restrict__ aout)
{
    __shared__ alignas(16) unsigned short Ks[2][4096];
    __shared__ alignas(16) unsigned short Vs[2][4096];

    int tid = threadIdx.x;
    int lane = tid & 63, w = tid >> 6;

    int bid = blockIdx.x;
    int xcd = bid & 7;
    int chunk = bid >> 3;            // [0,96)
    int bh = xcd * 12 + (chunk % 12);
    int qblk = chunk / 12;           // [0,8)
    int b = bh / H_, h = bh - b * H_;
    int q0w = qblk * 128 + w * 32;
    int l31 = lane & 31;
    int hi = lane >> 5;
    int swz = l31 & 7;

    const unsigned short* qp = qg + ((size_t)bh * N_ + q0w + l31) * HD + hi * 8;
    short8 qf[4];
    #pragma unroll
    for (int ds = 0; ds < 4; ds++)
        qf[ds] = *reinterpret_cast<const short8*>(qp + ds * 16);

    const unsigned short* kbh = kg + (size_t)bh * N_ * HD;
    const unsigned short* vtbh = vtg + (size_t)bh * HD * N_;

    int sr0 = tid >> 3;
    int sj0 = (tid & 7) ^ (sr0 & 7);
    int sr1 = sr0 + 32;
    int sj1 = (tid & 7) ^ (sr1 & 7);

    float m_run = -INFINITY, l_run = 0.f;
    f32x16 o0 = {}, o1 = {};

#define STAGE(buf, kv0)                                                        \
    do {                                                                       \
        gload16(kbh + (size_t)((kv0) + sr0) * HD + sj0 * 8, &Ks[buf][w * 512]);\
        gload16(kbh + (size_t)((kv0) + sr1) * HD + sj1 * 8, &Ks[buf][2048 + w * 512]);\
        gload16(vtbh + (size_t)sr0 * N_ + (kv0) + sj0 * 8, &Vs[buf][w * 512]); \
        gload16(vtbh + (size_t)sr1 * N_ + (kv0) + sj1 * 8, &Vs[buf][2048 + w * 512]);\
    } while (0)

    STAGE(0, 0);
    asm volatile("s_waitcnt vmcnt(0)" ::: "memory");
    __builtin_amdgcn_s_barrier();
    __builtin_amdgcn_sched_barrier(0);

    int cur = 0;
    for (int t = 0; t < 16; ++t) {
        if (t < 15) STAGE(cur ^ 1, (t + 1) * 64);

        const unsigned short* Ksb = Ks[cur];
        const unsigned short* Vsb = Vs[cur];

        f32x16 s0 = {}, s1 = {};
        #pragma unroll
        for (int ds = 0; ds < 4; ds++) {
            int pc = (ds * 2 + hi) ^ swz;
            short8 kf0 = *reinterpret_cast<const short8*>(&Ksb[(l31) * 64 + pc * 8]);
            short8 kf1 = *reinterpret_cast<const short8*>(&Ksb[(32 + l31) * 64 + pc * 8]);
            s0 = __builtin_amdgcn_mfma_f32_32x32x16_bf16(kf0, qf[ds], s0, 0, 0, 0);
            s1 = __builtin_amdgcn_mfma_f32_32x32x16_bf16(kf1, qf[ds], s1, 0, 0, 0);
        }

        float mx = s0[0];
        #pragma unroll
        for (int r = 1; r < 16; r++) mx = fmaxf(mx, s0[r]);
        #pragma unroll
        for (int r = 0; r < 16; r++) mx = fmaxf(mx, s1[r]);
        mx = fmaxf(mx, __shfl_xor(mx, 32, 64));

        if (__any(mx > m_run + 8.f)) {
            float mn = fmaxf(m_run, mx);
            float al = exp2_hw(m_run - mn);
            m_run = mn;
            l_run *= al;
            o0 *= al;
            o1 *= al;
        }

        float psum = 0.f;
        #pragma unroll
        for (int r = 0; r < 16; r++) { float p = exp2_hw(s0[r] - m_run); psum += p; s0[r] = p; }
        #pragma unroll
        for (int r = 0; r < 16; r++) { float p = exp2_hw(s1[r] - m_run); psum += p; s1[r] = p; }

        l_run += psum + __shfl_xor(psum, 32, 64);

        unsigned int c0[8], c1[8];
        #pragma unroll
        for (int i = 0; i < 8; i++) c0[i] = cvtpk_bf16(s0[2 * i], s0[2 * i + 1]);
        #pragma unroll
        for (int i = 0; i < 8; i++) c1[i] = cvtpk_bf16(s1[2 * i], s1[2 * i + 1]);
        PLSWAP(c0[0], c0[2]); PLSWAP(c0[1], c0[3]);
        PLSWAP(c0[4], c0[6]); PLSWAP(c0[5], c0[7]);
        PLSWAP(c1[0], c1[2]); PLSWAP(c1[1], c1[3]);
        PLSWAP(c1[4], c1[6]); PLSWAP(c1[5], c1[7]);
        short8 pa0 = pack4(c0[0], c0[1], c0[2], c0[3]);
        short8 pa1 = pack4(c0[4], c0[5], c0[6], c0[7]);
        short8 pa2 = pack4(c1[0], c1[1], c1[2], c1[3]);
        short8 pa3 = pack4(c1[4], c1[5], c1[6], c1[7]);

        #pragma unroll
        for (int ks = 0; ks < 4; ks++) {
            int pc = (ks * 2 + hi) ^ swz;
            short8 vf0 = *reinterpret_cast<const short8*>(&Vsb[(l31) * 64 + pc * 8]);
            short8 vf1 = *reinterpret_cast<const short8*>(&Vsb[(32 + l31) * 64 + pc * 8]);
            short8 pa = (ks == 0) ? pa0 : (ks == 1) ? pa1 : (ks == 2) ? pa2 : pa3;
            o0 = __builtin_amdgcn_mfma_f32_32x32x16_bf16(vf0, pa, o0, 0, 0, 0);
            o1 = __builtin_amdgcn_mfma_f32_32x32x16_bf16(vf1, pa, o1, 0, 0, 0);
        }

        if (t < 15) {
            asm volatile("s_waitcnt vmcnt(0)" ::: "memory");
            __builtin_amdgcn_s_barrier();
            __builtin_amdgcn_sched_barrier(0);
            cur ^= 1;
        }
    }
#undef STAGE

    float linv = 1.0f / l_run;
    unsigned short* op = aout + ((size_t)(b * N_ + q0w + l31)) * D_ + h * HD;
    #pragma unroll
    for (int rg = 0; rg < 4; rg++) {
        int dbase = 8 * rg + 4 * hi;
        unsigned long long u0 = 0, u1 = 0;
        #pragma unroll
        for (int k = 0; k < 4; k++) {
            u0 |= (unsigned long long)f2bf(o0[rg * 4 + k] * linv) << (16 * k);
            u1 |= (unsigned long long)f2bf(o1[rg * 4 + k] * linv) << (16 * k);
        }
        *reinterpret_cast<unsigned long long*>(op + dbase) = u0;
        *reinterpret_cast<unsigned long long*>(op + 32 + dbase) = u1;
    }
}

// ---------------- launch ----------------

extern "C" void kernel_launch(void* const* d_in, const int* in_sizes, int n_in,
                              void* d_out, int out_size, void* d_ws, size_t ws_size,
                              hipStream_t stream) {
    const float* x      = (const float*)d_in[0];
    const float* w_qkv  = (const float*)d_in[1];
    const float* b_qkv  = (const float*)d_in[2];
    const float* w_proj = (const float*)d_in[3];
    const float* b_proj = (const float*)d_in[4];
    float* out = (float*)d_out;

    char* ws = (char*)d_ws;
    unsigned short* xb     = (unsigned short*)(ws + 0);          // 12.6 MB
    unsigned short* wqkvT  = (unsigned short*)(ws + 12582912);   // 3.5 MB
    unsigned short* wprojT = (unsigned short*)(ws + 16121856);   // 1.2 MB
    unsigned short* qb     = (unsigned short*)(ws + 17301504);   // 12.6 MB
    unsigned short* kb     = (unsigned short*)(ws + 29884416);   // 12.6 MB
    unsigned short* vtb    = (unsigned short*)(ws + 42467328);   // 12.6 MB (end ~55 MB)
    unsigned short* aout   = xb;  // x dead after gemm<0>

    prep_kernel<<<15360, 256, 0, stream>>>(x, w_qkv, w_proj, xb, wqkvT, wprojT);

    gemm_kernel<0><<<1152, 256, 0, stream>>>(
        xb, wqkvT, b_qkv, nullptr, qb, kb, vtb, 3 * D_, D_);

    attn_kernel<<<768, 256, 0, stream>>>(qb, kb, vtb, aout);

    gemm_kernel<1><<<384, 256, 0, stream>>>(
        aout, wprojT, b_proj, out, nullptr, nullptr, nullptr, D_, D_);
}